// Round 2
// baseline (82357.471 us; speedup 1.0000x reference)
//
#include <hip/hip_runtime.h>

#define T_SEQ   1024
#define T_STEPS 1023
#define BATCH   128
#define DIM     256
#define HID     1024
#define VOUT    128
#define KTOT    1280   // 256 (x) + 1024 (h)
#define NKK     40     // KTOT / 32
#define WGS     256    // persistent workgroups (1 per CU)

typedef __attribute__((ext_vector_type(8))) short short8;
typedef __attribute__((ext_vector_type(4))) float floatx4;

__device__ __forceinline__ unsigned short f2bf(float x) {
    union { float f; unsigned u; } v; v.f = x;
    unsigned r = v.u + 0x7FFFu + ((v.u >> 16) & 1u);   // RNE
    return (unsigned short)(r >> 16);
}
__device__ __forceinline__ float sigm(float x) { return 1.0f / (1.0f + __expf(-x)); }

// ---------------- prep kernels ----------------

// Pack gate weights bf16 in WAVE-FRAGMENT order:
// element (g7, cw, kk, lane, j) = W[col = cw*16 + (lane&15)][k = kk*32 + (lane>>4)*8 + j]
// where col c in [0,32): gate = c>>3, jj = c&7, W-row R = gate*1024 + g7*8 + jj;
// k < 256 -> W_ih, else W_hh. This makes both the LDS staging copy and the
// per-wave ds_read_b128 fragment fetch perfectly linear (conflict-free).
__global__ void pack_w(const float* __restrict__ Wih, const float* __restrict__ Whh,
                       unsigned short* __restrict__ Wp) {
    const size_t idx = (size_t)blockIdx.x * 256 + threadIdx.x;
    if (idx >= (size_t)128 * 2 * NKK * 64 * 8) return;   // 5,242,880
    const int j  = (int)(idx & 7);
    const int l  = (int)((idx >> 3) & 63);
    const int rest = (int)(idx >> 9);
    const int kk  = rest % NKK;
    const int gcw = rest / NKK;
    const int cw = gcw & 1, g7 = gcw >> 1;
    const int k   = kk * 32 + (l >> 4) * 8 + j;
    const int col = cw * 16 + (l & 15);
    const int gate = col >> 3, jj = col & 7;
    const int R = gate * HID + g7 * 8 + jj;
    const float v = (k < DIM) ? Wih[(size_t)R * DIM + k] : Whh[(size_t)R * HID + (k - DIM)];
    Wp[idx] = f2bf(v);
}

__global__ void pack_bias(const float* __restrict__ bih, const float* __restrict__ bhh,
                          float* __restrict__ bc) {
    const int idx = blockIdx.x * 256 + threadIdx.x;
    if (idx >= 4096) return;
    const int c = idx & 31, g7 = idx >> 5;
    const int gate = c >> 3, jj = c & 7;
    const int R = gate * HID + g7 * 8 + jj;
    bc[idx] = bih[R] + bhh[R];
}

__global__ void pack_wout(const float* __restrict__ Wo, unsigned short* __restrict__ WoBf) {
    const int idx = blockIdx.x * 256 + threadIdx.x;
    if (idx < VOUT * HID) WoBf[idx] = f2bf(Wo[idx]);
}

// sequence [B, T, D] fp32 -> Xbf [T-1, B, D] bf16 (time-major)
__global__ void pack_x(const float* __restrict__ seq, unsigned short* __restrict__ Xbf) {
    const size_t idx = (size_t)blockIdx.x * 256 + threadIdx.x;
    if (idx >= (size_t)T_STEPS * BATCH * DIM) return;
    const int k = (int)(idx & (DIM - 1));
    const int b = (int)((idx >> 8) & (BATCH - 1));
    const int t = (int)(idx >> 15);
    Xbf[idx] = f2bf(seq[((size_t)b * T_SEQ + t) * DIM + k]);
}

__global__ void init_state(unsigned short* __restrict__ Hb, int* __restrict__ bar) {
    const int idx = blockIdx.x * 256 + threadIdx.x;
    if (idx < BATCH * HID) Hb[idx] = 0;
    if (idx < WGS * 16) bar[idx] = 0;
}

// ---------------- persistent recurrent kernel ----------------
// 256 WGs x 512 threads, 1 WG/CU (LDS 90 KB caps occupancy at 1 -> all co-resident).
// WG (s = batch half, g7 = 8 h-cols -> 32 gate cols). Weights live in LDS.
// Cell state c lives in registers (1 elem/thread). Grid barrier between steps:
// distributed arrive flags + agent-scope atomics + __threadfence release/acquire.
__global__ __launch_bounds__(512, 1) void lstm_persist(
    const unsigned short* __restrict__ Xbf,
    unsigned short* __restrict__ Hb,
    const unsigned short* __restrict__ Wp,
    const float* __restrict__ bc,
    int* __restrict__ bar)
{
    __shared__ short8 Wl[2 * NKK * 64];   // 80 KB: [cw][kk][lane] 16B frags
    __shared__ float gl[64][33];          // 8.4 KB gate staging
    __shared__ int abortf;

    const int wg = blockIdx.x;
    const int s  = wg & 1;
    const int g7 = wg >> 1;
    const int tid = threadIdx.x;
    const int w  = tid >> 6;
    const int l  = tid & 63;
    const int lr = l & 15;
    const int lq = l >> 4;
    const int rw = w >> 1;
    const int cw = w & 1;
    const int arow = s * 64 + rw * 16 + lr;

    // stage this WG's 80 KB weight slice into LDS (one time)
    const short8* wpg = (const short8*)(Wp + (size_t)g7 * (2 * NKK * 64 * 8));
    for (int i = tid; i < 2 * NKK * 64; i += 512) Wl[i] = wpg[i];

    // epilogue constants: thread owns (row er, h-col jj) of the 64x8 block
    const int er  = tid >> 3;
    const int ejj = tid & 7;
    const float bi = bc[g7 * 32 + 0  + ejj];
    const float bf = bc[g7 * 32 + 8  + ejj];
    const float bg = bc[g7 * 32 + 16 + ejj];
    const float bo_ = bc[g7 * 32 + 24 + ejj];
    const size_t ecid = (size_t)(s * 64 + er) * HID + g7 * 8 + ejj;
    float creg = 0.f;

    const short8* wb = Wl + cw * NKK * 64 + l;
    if (tid == 0) abortf = 0;
    __syncthreads();

    long budget = 1L << 24;   // spin safety: abort (fail verify) instead of hang
    for (int t = 0; t < T_STEPS; ++t) {
        const short8* axv = (const short8*)(Xbf + ((size_t)t * BATCH + arow) * DIM) + lq;
        const short8* ahv = (const short8*)(Hb + (size_t)t * BATCH * HID + (size_t)arow * HID) + lq;

        floatx4 ac0 = {0.f, 0.f, 0.f, 0.f}, ac1 = {0.f, 0.f, 0.f, 0.f};
        #pragma unroll
        for (int kk = 0; kk < 8; kk += 2) {   // x part
            ac0 = __builtin_amdgcn_mfma_f32_16x16x32_bf16(axv[kk * 4],     wb[kk * 64],       ac0, 0, 0, 0);
            ac1 = __builtin_amdgcn_mfma_f32_16x16x32_bf16(axv[kk * 4 + 4], wb[(kk + 1) * 64], ac1, 0, 0, 0);
        }
        #pragma unroll 8
        for (int kk = 0; kk < 32; kk += 2) {  // h part
            ac0 = __builtin_amdgcn_mfma_f32_16x16x32_bf16(ahv[kk * 4],     wb[(8 + kk) * 64], ac0, 0, 0, 0);
            ac1 = __builtin_amdgcn_mfma_f32_16x16x32_bf16(ahv[kk * 4 + 4], wb[(9 + kk) * 64], ac1, 0, 0, 0);
        }

        #pragma unroll
        for (int r = 0; r < 4; ++r)
            gl[rw * 16 + lq * 4 + r][cw * 16 + lr] = ac0[r] + ac1[r];
        __syncthreads();

        // fused cell update
        const float gi = gl[er][0  + ejj] + bi;
        const float gf = gl[er][8  + ejj] + bf;
        const float gg = gl[er][16 + ejj] + bg;
        const float go = gl[er][24 + ejj] + bo_;
        const float iv = sigm(gi), fv = sigm(gf), ov = sigm(go);
        const float gv = tanhf(gg);
        creg = fv * creg + iv * gv;
        Hb[(size_t)(t + 1) * BATCH * HID + ecid] = f2bf(ov * tanhf(creg));

        // ---- grid barrier ----
        __threadfence();   // release: make h stores agent-visible (L2 wb)
        if (tid == 0)
            __hip_atomic_store(&bar[wg * 16], t + 1, __ATOMIC_RELAXED, __HIP_MEMORY_SCOPE_AGENT);
        if (tid < WGS) {
            while (__hip_atomic_load(&bar[tid * 16], __ATOMIC_RELAXED, __HIP_MEMORY_SCOPE_AGENT) < t + 1) {
                __builtin_amdgcn_s_sleep(1);
                if (--budget < 0) { abortf = 1; break; }
            }
        }
        __syncthreads();   // also protects gl reuse next iteration
        __threadfence();   // acquire: invalidate L1/L2 before reading fresh h
        if (abortf) break;
    }
}

// ---------------- deferred head: logits + log-softmax ----------------
__global__ __launch_bounds__(256, 2) void head_ls(
    const unsigned short* __restrict__ Hb,
    const unsigned short* __restrict__ Wo,
    const float* __restrict__ bo,
    float* __restrict__ out)
{
    const int bg = blockIdx.x;    // 0..7
    const int t  = blockIdx.y;    // 0..1022
    const int tid = threadIdx.x;
    const int w  = tid >> 6;
    const int l  = tid & 63;
    const int lr = l & 15;
    const int lq = l >> 4;
    const int b0 = bg * 16;

    const unsigned short* ap  = Hb + (size_t)(t + 1) * BATCH * HID + (size_t)(b0 + lr) * HID + lq * 8;
    const unsigned short* bp0 = Wo + (size_t)(w * 32 + lr) * HID + lq * 8;
    const unsigned short* bp1 = Wo + (size_t)(w * 32 + 16 + lr) * HID + lq * 8;

    floatx4 a0 = {0.f, 0.f, 0.f, 0.f}, a1 = {0.f, 0.f, 0.f, 0.f};
    #pragma unroll 8
    for (int kk = 0; kk < 32; ++kk) {
        short8 a   = *(const short8*)(ap  + kk * 32);
        short8 b0v = *(const short8*)(bp0 + kk * 32);
        short8 b1v = *(const short8*)(bp1 + kk * 32);
        a0 = __builtin_amdgcn_mfma_f32_16x16x32_bf16(a, b0v, a0, 0, 0, 0);
        a1 = __builtin_amdgcn_mfma_f32_16x16x32_bf16(a, b1v, a1, 0, 0, 0);
    }

    __shared__ float lg[16][132];
    #pragma unroll
    for (int r = 0; r < 4; ++r) {
        lg[lq * 4 + r][w * 32 + lr]      = a0[r] + bo[w * 32 + lr];
        lg[lq * 4 + r][w * 32 + 16 + lr] = a1[r] + bo[w * 32 + 16 + lr];
    }
    __syncthreads();

    const int row = tid >> 4;
    const int c   = tid & 15;
    float vals[8];
    float m = -1e30f;
    #pragma unroll
    for (int jv = 0; jv < 8; ++jv) { vals[jv] = lg[row][c + jv * 16]; m = fmaxf(m, vals[jv]); }
    #pragma unroll
    for (int d = 8; d >= 1; d >>= 1) m = fmaxf(m, __shfl_xor(m, d, 16));
    float ssum = 0.f;
    #pragma unroll
    for (int jv = 0; jv < 8; ++jv) ssum += __expf(vals[jv] - m);
    #pragma unroll
    for (int d = 8; d >= 1; d >>= 1) ssum += __shfl_xor(ssum, d, 16);
    const float lse = m + __logf(ssum);

    float* op = out + ((size_t)(b0 + row) * T_STEPS + t) * VOUT;
    #pragma unroll
    for (int jv = 0; jv < 8; ++jv) op[c + jv * 16] = vals[jv] - lse;
}

// ---------------- launcher ----------------
extern "C" void kernel_launch(void* const* d_in, const int* in_sizes, int n_in,
                              void* d_out, int out_size, void* d_ws, size_t ws_size,
                              hipStream_t stream) {
    const float* seq  = (const float*)d_in[0];
    const float* Wih  = (const float*)d_in[1];
    const float* Whh  = (const float*)d_in[2];
    const float* bih  = (const float*)d_in[3];
    const float* bhh  = (const float*)d_in[4];
    const float* Wout = (const float*)d_in[5];
    const float* bout = (const float*)d_in[6];
    float* out = (float*)d_out;

    char* p = (char*)d_ws;
    unsigned short* Wp   = (unsigned short*)p; p += (size_t)128 * 2 * NKK * 64 * 8 * 2;      // 10.5 MB
    unsigned short* WoBf = (unsigned short*)p; p += (size_t)VOUT * HID * 2;                  // 256 KB
    float*          bc   = (float*)p;          p += (size_t)4096 * 4;                        // 16 KB
    int*            bar  = (int*)p;            p += (size_t)WGS * 16 * 4;                    // 16 KB
    unsigned short* Xbf  = (unsigned short*)p; p += (size_t)T_STEPS * BATCH * DIM * 2;       // 67 MB
    unsigned short* Hb   = (unsigned short*)p; p += (size_t)(T_STEPS + 1) * BATCH * HID * 2; // 268 MB

    pack_w    <<<20480, 256, 0, stream>>>(Wih, Whh, Wp);
    pack_bias <<<16,    256, 0, stream>>>(bih, bhh, bc);
    pack_wout <<<512,   256, 0, stream>>>(Wout, WoBf);
    pack_x    <<<130944,256, 0, stream>>>(seq, Xbf);
    init_state<<<512,   256, 0, stream>>>(Hb, bar);

    lstm_persist<<<WGS, 512, 0, stream>>>(Xbf, Hb, Wp, bc, bar);

    head_ls<<<dim3(8, T_STEPS), 256, 0, stream>>>(Hb, WoBf, bout, out);
}

// Round 3
// 22252.943 us; speedup vs baseline: 3.7010x; 3.7010x over previous
//
#include <hip/hip_runtime.h>

#define T_SEQ   1024
#define T_STEPS 1023
#define BATCH   128
#define DIM     256
#define HID     1024
#define VOUT    128
#define KTOT    1280   // 256 (x) + 1024 (h)
#define NKK     40     // KTOT / 32
#define WGS     256    // persistent workgroups (1 per CU)

typedef __attribute__((ext_vector_type(8))) short short8;
typedef __attribute__((ext_vector_type(4))) float floatx4;

__device__ __forceinline__ unsigned short f2bf(float x) {
    union { float f; unsigned u; } v; v.f = x;
    unsigned r = v.u + 0x7FFFu + ((v.u >> 16) & 1u);   // RNE
    return (unsigned short)(r >> 16);
}
__device__ __forceinline__ float sigm(float x) { return 1.0f / (1.0f + __expf(-x)); }

// ---------------- prep kernels ----------------

// Pack gate weights bf16 in WAVE-FRAGMENT order:
// element (g7, cw, kk, lane, j) = W[col = cw*16 + (lane&15)][k = kk*32 + (lane>>4)*8 + j]
// col c in [0,32): gate = c>>3, jj = c&7, W-row R = gate*1024 + g7*8 + jj;
// k < 256 -> W_ih, else W_hh.
__global__ void pack_w(const float* __restrict__ Wih, const float* __restrict__ Whh,
                       unsigned short* __restrict__ Wp) {
    const size_t idx = (size_t)blockIdx.x * 256 + threadIdx.x;
    if (idx >= (size_t)128 * 2 * NKK * 64 * 8) return;   // 5,242,880
    const int j  = (int)(idx & 7);
    const int l  = (int)((idx >> 3) & 63);
    const int rest = (int)(idx >> 9);
    const int kk  = rest % NKK;
    const int gcw = rest / NKK;
    const int cw = gcw & 1, g7 = gcw >> 1;
    const int k   = kk * 32 + (l >> 4) * 8 + j;
    const int col = cw * 16 + (l & 15);
    const int gate = col >> 3, jj = col & 7;
    const int R = gate * HID + g7 * 8 + jj;
    const float v = (k < DIM) ? Wih[(size_t)R * DIM + k] : Whh[(size_t)R * HID + (k - DIM)];
    Wp[idx] = f2bf(v);
}

__global__ void pack_bias(const float* __restrict__ bih, const float* __restrict__ bhh,
                          float* __restrict__ bc) {
    const int idx = blockIdx.x * 256 + threadIdx.x;
    if (idx >= 4096) return;
    const int c = idx & 31, g7 = idx >> 5;
    const int gate = c >> 3, jj = c & 7;
    const int R = gate * HID + g7 * 8 + jj;
    bc[idx] = bih[R] + bhh[R];
}

__global__ void pack_wout(const float* __restrict__ Wo, unsigned short* __restrict__ WoBf) {
    const int idx = blockIdx.x * 256 + threadIdx.x;
    if (idx < VOUT * HID) WoBf[idx] = f2bf(Wo[idx]);
}

// sequence [B, T, D] fp32 -> Xbf [T-1, B, D] bf16 (time-major)
__global__ void pack_x(const float* __restrict__ seq, unsigned short* __restrict__ Xbf) {
    const size_t idx = (size_t)blockIdx.x * 256 + threadIdx.x;
    if (idx >= (size_t)T_STEPS * BATCH * DIM) return;
    const int k = (int)(idx & (DIM - 1));
    const int b = (int)((idx >> 8) & (BATCH - 1));
    const int t = (int)(idx >> 15);
    Xbf[idx] = f2bf(seq[((size_t)b * T_SEQ + t) * DIM + k]);
}

__global__ void init_state(unsigned short* __restrict__ Hb, int* __restrict__ bar) {
    const int idx = blockIdx.x * 256 + threadIdx.x;
    if (idx < BATCH * HID) Hb[idx] = 0;
    if (idx < WGS * 16) bar[idx] = 0;
}

// ---------------- persistent recurrent kernel ----------------
// 256 WGs x 512 threads, 1 WG/CU (90 KB LDS caps occupancy -> all co-resident).
// Grid barrier: single monotone counter; thread 0 of each WG does
// fence(release) -> relaxed atomicAdd -> poll one line -> fence(acquire).
__global__ __launch_bounds__(512, 1) void lstm_persist(
    const unsigned short* __restrict__ Xbf,
    unsigned short* __restrict__ Hb,
    const unsigned short* __restrict__ Wp,
    const float* __restrict__ bc,
    int* __restrict__ bar)
{
    __shared__ short8 Wl[2 * NKK * 64];   // 80 KB: [cw][kk][lane] 16B frags
    __shared__ float gl[64][33];          // 8.4 KB gate staging
    __shared__ int abortf;

    const int wg = blockIdx.x;
    const int s  = wg & 1;
    const int g7 = wg >> 1;
    const int tid = threadIdx.x;
    const int w  = tid >> 6;
    const int l  = tid & 63;
    const int lr = l & 15;
    const int lq = l >> 4;
    const int rw = w >> 1;
    const int cw = w & 1;
    const int arow = s * 64 + rw * 16 + lr;

    // stage this WG's 80 KB weight slice into LDS (one time)
    const short8* wpg = (const short8*)(Wp + (size_t)g7 * (2 * NKK * 64 * 8));
    for (int i = tid; i < 2 * NKK * 64; i += 512) Wl[i] = wpg[i];

    // epilogue constants: thread owns (row er, h-col ejj) of the 64x8 block
    const int er  = tid >> 3;
    const int ejj = tid & 7;
    const float bi = bc[g7 * 32 + 0  + ejj];
    const float bf = bc[g7 * 32 + 8  + ejj];
    const float bg = bc[g7 * 32 + 16 + ejj];
    const float bo_ = bc[g7 * 32 + 24 + ejj];
    const size_t ecid = (size_t)(s * 64 + er) * HID + g7 * 8 + ejj;
    float creg = 0.f;

    const short8* wb = Wl + cw * NKK * 64 + l;
    if (tid == 0) abortf = 0;
    __syncthreads();

    long budget = 1L << 22;   // spin safety: abort (fail verify) instead of hang
    for (int t = 0; t < T_STEPS; ++t) {
        const short8* axv = (const short8*)(Xbf + ((size_t)t * BATCH + arow) * DIM) + lq;
        const short8* ahv = (const short8*)(Hb + (size_t)t * BATCH * HID + (size_t)arow * HID) + lq;

        floatx4 ac0 = {0.f, 0.f, 0.f, 0.f}, ac1 = {0.f, 0.f, 0.f, 0.f};
        #pragma unroll
        for (int kk = 0; kk < 8; kk += 2) {   // x part
            ac0 = __builtin_amdgcn_mfma_f32_16x16x32_bf16(axv[kk * 4],     wb[kk * 64],       ac0, 0, 0, 0);
            ac1 = __builtin_amdgcn_mfma_f32_16x16x32_bf16(axv[kk * 4 + 4], wb[(kk + 1) * 64], ac1, 0, 0, 0);
        }
        #pragma unroll 8
        for (int kk = 0; kk < 32; kk += 2) {  // h part
            ac0 = __builtin_amdgcn_mfma_f32_16x16x32_bf16(ahv[kk * 4],     wb[(8 + kk) * 64], ac0, 0, 0, 0);
            ac1 = __builtin_amdgcn_mfma_f32_16x16x32_bf16(ahv[kk * 4 + 4], wb[(9 + kk) * 64], ac1, 0, 0, 0);
        }

        #pragma unroll
        for (int r = 0; r < 4; ++r)
            gl[rw * 16 + lq * 4 + r][cw * 16 + lr] = ac0[r] + ac1[r];
        __syncthreads();

        // fused cell update (thread -> row er, h-col ejj)
        const float gi = gl[er][0  + ejj] + bi;
        const float gf = gl[er][8  + ejj] + bf;
        const float gg = gl[er][16 + ejj] + bg;
        const float go = gl[er][24 + ejj] + bo_;
        const float iv = sigm(gi), fv = sigm(gf), ov = sigm(go);
        const float gv = tanhf(gg);
        creg = fv * creg + iv * gv;
        Hb[(size_t)(t + 1) * BATCH * HID + ecid] = f2bf(ov * tanhf(creg));

        // ---- grid barrier: single monotone counter ----
        __syncthreads();                       // drains vmcnt: all h stores in L2
        if (tid == 0) {
            __builtin_amdgcn_fence(__ATOMIC_RELEASE, "agent");   // L2 writeback
            __hip_atomic_fetch_add(&bar[0], 1, __ATOMIC_RELAXED, __HIP_MEMORY_SCOPE_AGENT);
            const int target = (t + 1) * WGS;
            while (__hip_atomic_load(&bar[0], __ATOMIC_RELAXED, __HIP_MEMORY_SCOPE_AGENT) < target) {
                __builtin_amdgcn_s_sleep(2);
                if (--budget < 0) { abortf = 1; break; }
            }
            __builtin_amdgcn_fence(__ATOMIC_ACQUIRE, "agent");   // L1/L2 invalidate
        }
        __syncthreads();                       // rest of WG waits on thread 0
        if (abortf) break;
    }
}

// ---------------- deferred head: logits + log-softmax ----------------
__global__ __launch_bounds__(256, 2) void head_ls(
    const unsigned short* __restrict__ Hb,
    const unsigned short* __restrict__ Wo,
    const float* __restrict__ bo,
    float* __restrict__ out)
{
    const int bg = blockIdx.x;    // 0..7
    const int t  = blockIdx.y;    // 0..1022
    const int tid = threadIdx.x;
    const int w  = tid >> 6;
    const int l  = tid & 63;
    const int lr = l & 15;
    const int lq = l >> 4;
    const int b0 = bg * 16;

    const unsigned short* ap  = Hb + (size_t)(t + 1) * BATCH * HID + (size_t)(b0 + lr) * HID + lq * 8;
    const unsigned short* bp0 = Wo + (size_t)(w * 32 + lr) * HID + lq * 8;
    const unsigned short* bp1 = Wo + (size_t)(w * 32 + 16 + lr) * HID + lq * 8;

    floatx4 a0 = {0.f, 0.f, 0.f, 0.f}, a1 = {0.f, 0.f, 0.f, 0.f};
    #pragma unroll 8
    for (int kk = 0; kk < 32; ++kk) {
        short8 a   = *(const short8*)(ap  + kk * 32);
        short8 b0v = *(const short8*)(bp0 + kk * 32);
        short8 b1v = *(const short8*)(bp1 + kk * 32);
        a0 = __builtin_amdgcn_mfma_f32_16x16x32_bf16(a, b0v, a0, 0, 0, 0);
        a1 = __builtin_amdgcn_mfma_f32_16x16x32_bf16(a, b1v, a1, 0, 0, 0);
    }

    __shared__ float lg[16][132];
    #pragma unroll
    for (int r = 0; r < 4; ++r) {
        lg[lq * 4 + r][w * 32 + lr]      = a0[r] + bo[w * 32 + lr];
        lg[lq * 4 + r][w * 32 + 16 + lr] = a1[r] + bo[w * 32 + 16 + lr];
    }
    __syncthreads();

    const int row = tid >> 4;
    const int c   = tid & 15;
    float vals[8];
    float m = -1e30f;
    #pragma unroll
    for (int jv = 0; jv < 8; ++jv) { vals[jv] = lg[row][c + jv * 16]; m = fmaxf(m, vals[jv]); }
    #pragma unroll
    for (int d = 8; d >= 1; d >>= 1) m = fmaxf(m, __shfl_xor(m, d, 16));
    float ssum = 0.f;
    #pragma unroll
    for (int jv = 0; jv < 8; ++jv) ssum += __expf(vals[jv] - m);
    #pragma unroll
    for (int d = 8; d >= 1; d >>= 1) ssum += __shfl_xor(ssum, d, 16);
    const float lse = m + __logf(ssum);

    float* op = out + ((size_t)(b0 + row) * T_STEPS + t) * VOUT;
    #pragma unroll
    for (int jv = 0; jv < 8; ++jv) op[c + jv * 16] = vals[jv] - lse;
}

// ---------------- launcher ----------------
extern "C" void kernel_launch(void* const* d_in, const int* in_sizes, int n_in,
                              void* d_out, int out_size, void* d_ws, size_t ws_size,
                              hipStream_t stream) {
    const float* seq  = (const float*)d_in[0];
    const float* Wih  = (const float*)d_in[1];
    const float* Whh  = (const float*)d_in[2];
    const float* bih  = (const float*)d_in[3];
    const float* bhh  = (const float*)d_in[4];
    const float* Wout = (const float*)d_in[5];
    const float* bout = (const float*)d_in[6];
    float* out = (float*)d_out;

    char* p = (char*)d_ws;
    unsigned short* Wp   = (unsigned short*)p; p += (size_t)128 * 2 * NKK * 64 * 8 * 2;      // 10.5 MB
    unsigned short* WoBf = (unsigned short*)p; p += (size_t)VOUT * HID * 2;                  // 256 KB
    float*          bc   = (float*)p;          p += (size_t)4096 * 4;                        // 16 KB
    int*            bar  = (int*)p;            p += (size_t)WGS * 16 * 4;                    // 16 KB
    unsigned short* Xbf  = (unsigned short*)p; p += (size_t)T_STEPS * BATCH * DIM * 2;       // 67 MB
    unsigned short* Hb   = (unsigned short*)p; p += (size_t)(T_STEPS + 1) * BATCH * HID * 2; // 268 MB

    pack_w    <<<20480, 256, 0, stream>>>(Wih, Whh, Wp);
    pack_bias <<<16,    256, 0, stream>>>(bih, bhh, bc);
    pack_wout <<<512,   256, 0, stream>>>(Wout, WoBf);
    pack_x    <<<130944,256, 0, stream>>>(seq, Xbf);
    init_state<<<512,   256, 0, stream>>>(Hb, bar);

    lstm_persist<<<WGS, 512, 0, stream>>>(Xbf, Hb, Wp, bc, bar);

    head_ls<<<dim3(8, T_STEPS), 256, 0, stream>>>(Hb, WoBf, bout, out);
}

// Round 4
// 6169.109 us; speedup vs baseline: 13.3500x; 3.6072x over previous
//
#include <hip/hip_runtime.h>

#define T_SEQ   1024
#define T_STEPS 1023
#define BATCH   128
#define DIM     256
#define HID     1024
#define VOUT    128
#define KTOT    1280   // 256 (x) + 1024 (h)
#define NKK     40     // KTOT / 32
#define WGS     256    // persistent workgroups (1 per CU)
#define HSLOT   131072 // ushorts per t-slot of blocked H: [s][g7][r:64][c:8]

typedef __attribute__((ext_vector_type(8))) short short8;
typedef __attribute__((ext_vector_type(4))) float floatx4;

__device__ __forceinline__ unsigned short f2bf(float x) {
    union { float f; unsigned u; } v; v.f = x;
    unsigned r = v.u + 0x7FFFu + ((v.u >> 16) & 1u);   // RNE
    return (unsigned short)(r >> 16);
}
__device__ __forceinline__ float sigm(float x) { return 1.0f / (1.0f + __expf(-x)); }

// ---------------- prep kernels ----------------

// Pack gate weights bf16 in WAVE-FRAGMENT order (unchanged from R3, verified):
// element (g7, cb, kk, lane, j) = W[col = cb*16 + (lane&15)][k = kk*32 + (lane>>4)*8 + j]
// col c in [0,32): gate = c>>3, jj = c&7, W-row R = gate*1024 + g7*8 + jj.
__global__ void pack_w(const float* __restrict__ Wih, const float* __restrict__ Whh,
                       unsigned short* __restrict__ Wp) {
    const size_t idx = (size_t)blockIdx.x * 256 + threadIdx.x;
    if (idx >= (size_t)128 * 2 * NKK * 64 * 8) return;   // 5,242,880
    const int j  = (int)(idx & 7);
    const int l  = (int)((idx >> 3) & 63);
    const int rest = (int)(idx >> 9);
    const int kk  = rest % NKK;
    const int gcw = rest / NKK;
    const int cb = gcw & 1, g7 = gcw >> 1;
    const int k   = kk * 32 + (l >> 4) * 8 + j;
    const int col = cb * 16 + (l & 15);
    const int gate = col >> 3, jj = col & 7;
    const int R = gate * HID + g7 * 8 + jj;
    const float v = (k < DIM) ? Wih[(size_t)R * DIM + k] : Whh[(size_t)R * HID + (k - DIM)];
    Wp[idx] = f2bf(v);
}

__global__ void pack_bias(const float* __restrict__ bih, const float* __restrict__ bhh,
                          float* __restrict__ bc) {
    const int idx = blockIdx.x * 256 + threadIdx.x;
    if (idx >= 4096) return;
    const int c = idx & 31, g7 = idx >> 5;
    const int gate = c >> 3, jj = c & 7;
    const int R = gate * HID + g7 * 8 + jj;
    bc[idx] = bih[R] + bhh[R];
}

__global__ void pack_wout(const float* __restrict__ Wo, unsigned short* __restrict__ WoBf) {
    const int idx = blockIdx.x * 256 + threadIdx.x;
    if (idx < VOUT * HID) WoBf[idx] = f2bf(Wo[idx]);
}

// sequence [B, T, D] fp32 -> Xbf [T-1, B, D] bf16 (time-major)
__global__ void pack_x(const float* __restrict__ seq, unsigned short* __restrict__ Xbf) {
    const size_t idx = (size_t)blockIdx.x * 256 + threadIdx.x;
    if (idx >= (size_t)T_STEPS * BATCH * DIM) return;
    const int k = (int)(idx & (DIM - 1));
    const int b = (int)((idx >> 8) & (BATCH - 1));
    const int t = (int)(idx >> 15);
    Xbf[idx] = f2bf(seq[((size_t)b * T_SEQ + t) * DIM + k]);
}

__global__ void init_state(unsigned short* __restrict__ Hb, int* __restrict__ bar) {
    const int idx = blockIdx.x * 256 + threadIdx.x;
    if (idx < HSLOT) Hb[idx] = 0;          // t=0 slot (blocked layout), zeros
    if (idx < 4096) bar[idx] = 0;          // barrier counters
}

// ---------------- persistent recurrent kernel ----------------
// 256 WGs x 512 threads, 1 WG/CU. Weights in LDS + 20 B-frags/wave in VGPRs.
// Wave (rw, kw): 16 rows x 32 cols x K-half (640). h exchanged via IC using
// device-coherent (agent-scope) stores into a WG-blocked layout -> NO cache
// fences, no L2 wb/inv. Two-level grid barrier (8 groups -> root).
__global__ __launch_bounds__(512, 1) void lstm_persist(
    const unsigned short* __restrict__ Xbf,
    unsigned short* __restrict__ Hblk,
    const unsigned short* __restrict__ Wp,
    const float* __restrict__ bc,
    int* __restrict__ bar)
{
    __shared__ short8 Wl[2 * NKK * 64];   // 80 KB weight slice
    __shared__ float gl[2][64][33];       // 16.9 KB: partial gate tiles (per K-half)
    __shared__ int abortf;

    const int wg = blockIdx.x;
    const int s  = wg & 1;
    const int g7 = wg >> 1;
    const int tid = threadIdx.x;
    const int w  = tid >> 6;
    const int l  = tid & 63;
    const int lr = l & 15;
    const int lq = l >> 4;
    const int rw = w >> 1;         // row group 0..3
    const int kw = w & 1;          // K-half 0..1
    const int arow = s * 64 + rw * 16 + lr;   // global batch row
    const int rr   = rw * 16 + lr;            // row within half

    // stage weight slice into LDS (once)
    const short8* wpg = (const short8*)(Wp + (size_t)g7 * (2 * NKK * 64 * 8));
    for (int i = tid; i < 2 * NKK * 64; i += 512) Wl[i] = wpg[i];

    // epilogue constants
    const int er  = tid >> 3;
    const int ejj = tid & 7;
    const float bi  = bc[g7 * 32 + 0  + ejj];
    const float bf  = bc[g7 * 32 + 8  + ejj];
    const float bg  = bc[g7 * 32 + 16 + ejj];
    const float bo_ = bc[g7 * 32 + 24 + ejj];
    float creg = 0.f;

    if (tid == 0) abortf = 0;
    __syncthreads();

    // hold this wave's col-block-0 B fragments in registers for all steps
    const short8* wl0 = Wl + (kw * 20) * 64 + l;              // col block 0
    const short8* wl1 = Wl + NKK * 64 + (kw * 20) * 64 + l;   // col block 1
    short8 breg[20];
    #pragma unroll
    for (int i = 0; i < 20; ++i) breg[i] = wl0[i * 64];

    long budget = 1L << 22;
    const int grp = wg >> 5;   // 8 groups of 32

    for (int t = 0; t < T_STEPS; ++t) {
        floatx4 ac0 = {0.f, 0.f, 0.f, 0.f}, ac1 = {0.f, 0.f, 0.f, 0.f};
        const short8* hbt = (const short8*)(Hblk + (size_t)t * HSLOT + (size_t)s * 65536)
                            + lq * 64 + rr;
        if (kw == 0) {
            const short8* axv = (const short8*)(Xbf + ((size_t)t * BATCH + arow) * DIM) + lq;
            #pragma unroll
            for (int i = 0; i < 8; ++i) {            // x part: kk 0..8
                short8 a = axv[i * 4];
                ac0 = __builtin_amdgcn_mfma_f32_16x16x32_bf16(a, breg[i],     ac0, 0, 0, 0);
                ac1 = __builtin_amdgcn_mfma_f32_16x16x32_bf16(a, wl1[i * 64], ac1, 0, 0, 0);
            }
            #pragma unroll
            for (int i = 0; i < 12; ++i) {           // h part: hk 0..12
                short8 a = hbt[i * 256];
                ac0 = __builtin_amdgcn_mfma_f32_16x16x32_bf16(a, breg[8 + i],       ac0, 0, 0, 0);
                ac1 = __builtin_amdgcn_mfma_f32_16x16x32_bf16(a, wl1[(8 + i) * 64], ac1, 0, 0, 0);
            }
        } else {
            #pragma unroll
            for (int i = 0; i < 20; ++i) {           // h part: hk 12..32
                short8 a = hbt[(12 + i) * 256];
                ac0 = __builtin_amdgcn_mfma_f32_16x16x32_bf16(a, breg[i],     ac0, 0, 0, 0);
                ac1 = __builtin_amdgcn_mfma_f32_16x16x32_bf16(a, wl1[i * 64], ac1, 0, 0, 0);
            }
        }

        // stage partial gate tiles (C/D layout: col=lane&15, row=lq*4+reg)
        #pragma unroll
        for (int r = 0; r < 4; ++r) {
            gl[kw][rw * 16 + lq * 4 + r][lr]      = ac0[r];
            gl[kw][rw * 16 + lq * 4 + r][16 + lr] = ac1[r];
        }
        __syncthreads();

        // fused cell update: thread -> (row er, h-col ejj); sum the two K-half partials
        const float g_i = gl[0][er][0  + ejj] + gl[1][er][0  + ejj] + bi;
        const float g_f = gl[0][er][8  + ejj] + gl[1][er][8  + ejj] + bf;
        const float g_g = gl[0][er][16 + ejj] + gl[1][er][16 + ejj] + bg;
        const float g_o = gl[0][er][24 + ejj] + gl[1][er][24 + ejj] + bo_;
        const float iv = sigm(g_i), fv = sigm(g_f), ov = sigm(g_o);
        const float gv = tanhf(g_g);
        creg = fv * creg + iv * gv;
        const unsigned hu = f2bf(ov * tanhf(creg));

        // write h block: pairs pack 2 bf16 -> one 4B device-coherent (IC) store.
        // Blocked layout: slot(t+1) + s*65536 + g7*512 + tid  (1 KB contiguous/WG)
        const unsigned up = (unsigned)__shfl_down((int)hu, 1);
        if ((tid & 1) == 0) {
            unsigned* hp = (unsigned*)(Hblk + (size_t)(t + 1) * HSLOT
                                       + (size_t)s * 65536 + (size_t)g7 * 512 + tid);
            __hip_atomic_store(hp, hu | (up << 16), __ATOMIC_RELAXED, __HIP_MEMORY_SCOPE_AGENT);
        }

        // ---- grid barrier (no cache fences: h went through to IC; addresses fresh) ----
        __syncthreads();   // drains vmcnt in every wave -> all h stores at IC
        if (tid == 0) {
            const int prev = __hip_atomic_fetch_add(&bar[grp * 64], 1,
                                 __ATOMIC_RELAXED, __HIP_MEMORY_SCOPE_AGENT);
            if (prev == 32 * (t + 1) - 1)
                __hip_atomic_fetch_add(&bar[1024], 1,
                                 __ATOMIC_RELAXED, __HIP_MEMORY_SCOPE_AGENT);
            while (__hip_atomic_load(&bar[1024], __ATOMIC_RELAXED,
                                     __HIP_MEMORY_SCOPE_AGENT) < 8 * (t + 1)) {
                __builtin_amdgcn_s_sleep(2);
                if (--budget < 0) { abortf = 1; break; }
            }
        }
        __syncthreads();
        if (abortf) break;
    }
}

// ---------------- deferred head: logits + log-softmax ----------------
__global__ __launch_bounds__(256, 2) void head_ls(
    const unsigned short* __restrict__ Hblk,
    const unsigned short* __restrict__ Wo,
    const float* __restrict__ bo,
    float* __restrict__ out)
{
    const int bg = blockIdx.x;    // 0..7
    const int t  = blockIdx.y;    // 0..1022
    const int tid = threadIdx.x;
    const int w  = tid >> 6;
    const int l  = tid & 63;
    const int lr = l & 15;
    const int lq = l >> 4;
    const int b0 = bg * 16;
    const int s  = b0 >> 6;
    const int r0 = b0 & 63;

    // A from blocked H layout: elem(kk,lq,row) at (kk*4+lq)*512 + row*8
    const short8* ap = (const short8*)(Hblk + (size_t)(t + 1) * HSLOT + (size_t)s * 65536)
                       + lq * 64 + (r0 + lr);
    const unsigned short* bp0 = Wo + (size_t)(w * 32 + lr) * HID + lq * 8;
    const unsigned short* bp1 = Wo + (size_t)(w * 32 + 16 + lr) * HID + lq * 8;

    floatx4 a0 = {0.f, 0.f, 0.f, 0.f}, a1 = {0.f, 0.f, 0.f, 0.f};
    #pragma unroll 8
    for (int kk = 0; kk < 32; ++kk) {
        short8 a   = ap[kk * 256];
        short8 b0v = *(const short8*)(bp0 + kk * 32);
        short8 b1v = *(const short8*)(bp1 + kk * 32);
        a0 = __builtin_amdgcn_mfma_f32_16x16x32_bf16(a, b0v, a0, 0, 0, 0);
        a1 = __builtin_amdgcn_mfma_f32_16x16x32_bf16(a, b1v, a1, 0, 0, 0);
    }

    __shared__ float lg[16][132];
    #pragma unroll
    for (int r = 0; r < 4; ++r) {
        lg[lq * 4 + r][w * 32 + lr]      = a0[r] + bo[w * 32 + lr];
        lg[lq * 4 + r][w * 32 + 16 + lr] = a1[r] + bo[w * 32 + 16 + lr];
    }
    __syncthreads();

    const int row = tid >> 4;
    const int c   = tid & 15;
    float vals[8];
    float m = -1e30f;
    #pragma unroll
    for (int jv = 0; jv < 8; ++jv) { vals[jv] = lg[row][c + jv * 16]; m = fmaxf(m, vals[jv]); }
    #pragma unroll
    for (int d = 8; d >= 1; d >>= 1) m = fmaxf(m, __shfl_xor(m, d, 16));
    float ssum = 0.f;
    #pragma unroll
    for (int jv = 0; jv < 8; ++jv) ssum += __expf(vals[jv] - m);
    #pragma unroll
    for (int d = 8; d >= 1; d >>= 1) ssum += __shfl_xor(ssum, d, 16);
    const float lse = m + __logf(ssum);

    float* op = out + ((size_t)(b0 + row) * T_STEPS + t) * VOUT;
    #pragma unroll
    for (int jv = 0; jv < 8; ++jv) op[c + jv * 16] = vals[jv] - lse;
}

// ---------------- launcher ----------------
extern "C" void kernel_launch(void* const* d_in, const int* in_sizes, int n_in,
                              void* d_out, int out_size, void* d_ws, size_t ws_size,
                              hipStream_t stream) {
    const float* seq  = (const float*)d_in[0];
    const float* Wih  = (const float*)d_in[1];
    const float* Whh  = (const float*)d_in[2];
    const float* bih  = (const float*)d_in[3];
    const float* bhh  = (const float*)d_in[4];
    const float* Wout = (const float*)d_in[5];
    const float* bout = (const float*)d_in[6];
    float* out = (float*)d_out;

    char* p = (char*)d_ws;
    unsigned short* Wp   = (unsigned short*)p; p += (size_t)128 * 2 * NKK * 64 * 8 * 2;      // 10.5 MB
    unsigned short* WoBf = (unsigned short*)p; p += (size_t)VOUT * HID * 2;                  // 256 KB
    float*          bc   = (float*)p;          p += (size_t)4096 * 4;                        // 16 KB
    int*            bar  = (int*)p;            p += (size_t)4096 * 4;                        // 16 KB
    unsigned short* Xbf  = (unsigned short*)p; p += (size_t)T_STEPS * BATCH * DIM * 2;       // 67 MB
    unsigned short* Hblk = (unsigned short*)p; p += (size_t)(T_STEPS + 1) * HSLOT * 2;       // 268 MB

    pack_w    <<<20480, 256, 0, stream>>>(Wih, Whh, Wp);
    pack_bias <<<16,    256, 0, stream>>>(bih, bhh, bc);
    pack_wout <<<512,   256, 0, stream>>>(Wout, WoBf);
    pack_x    <<<130944,256, 0, stream>>>(seq, Xbf);
    init_state<<<512,   256, 0, stream>>>(Hblk, bar);

    lstm_persist<<<WGS, 512, 0, stream>>>(Xbf, Hblk, Wp, bc, bar);

    head_ls<<<dim3(8, T_STEPS), 256, 0, stream>>>(Hblk, WoBf, bout, out);
}